// Round 18
// baseline (1504.779 us; speedup 1.0000x reference)
//
#include <hip/hip_runtime.h>
#include <hip/hip_cooperative_groups.h>
#include <stdint.h>

namespace cg = cooperative_groups;
typedef unsigned long long ull;

static __device__ __forceinline__ ull packkey(float f, int v) {
    uint32_t u = __float_as_uint(f);
    u = (u & 0x80000000u) ? ~u : (u | 0x80000000u);
    return ((ull)u << 32) | (ull)(~(uint32_t)v);
}
static __device__ __forceinline__ unsigned aloadu32(const unsigned* p) {
    return __hip_atomic_load(p, __ATOMIC_RELAXED, __HIP_MEMORY_SCOPE_AGENT);
}

// ---------------- build: in-degree of absorption DAG into pred field (word>>16) ----------------
__global__ void k_build4(const int* __restrict__ neighs, const float* __restrict__ hier,
                         unsigned* __restrict__ word, long E4, int K) {
    long t = (long)blockIdx.x * blockDim.x + threadIdx.x;
    if (t >= E4) return;
    long e = t * 4;
    int u = (int)(e / K);
    ull ku = packkey(hier[u], u);
    int4 w4 = *(const int4*)(neighs + e);
    int ws[4] = {w4.x, w4.y, w4.z, w4.w};
    #pragma unroll
    for (int j = 0; j < 4; j++) {
        int w = ws[j];
        if (w < 0) continue;
        if (ku > packkey(hier[w], w))
            atomicAdd(&word[w], 0x10000u);     // fire-and-forget
    }
}
__global__ void k_build1(const int* __restrict__ neighs, const float* __restrict__ hier,
                         unsigned* __restrict__ word, long E, int K) {
    long e = (long)blockIdx.x * blockDim.x + threadIdx.x;
    if (e >= E) return;
    int w = neighs[e];
    if (w < 0) return;
    int u = (int)(e / K);
    if (packkey(hier[u], u) > packkey(hier[w], w))
        atomicAdd(&word[w], 0x10000u);
}

// ---------------- propagation: owner polls word; fused adds + center maxes ----------------
// word[v] = pred<<16 | cenCount.  ABSORBED: cen>0.  CENTER: word==0.
__global__ __launch_bounds__(256, 8)
void k_propagate(const int* __restrict__ neighs, const float* __restrict__ hier,
                 unsigned* __restrict__ word, ull* __restrict__ best,
                 int V, int K) {
    const int gtid = blockIdx.x * blockDim.x + threadIdx.x;
    const int wv = gtid >> 6, lane = gtid & 63;
    const int gb = wv << 6;
    if (gb >= V) return;                     // wave owns nothing; exit immediately
    int v = gb + lane;
    bool pend = v < V;

    long sweeps = 0;
    while (__any(pend)) {
        unsigned wd = 0x7FFF0000u;
        if (pend) wd = aloadu32(&word[v]);
        bool absn = pend && ((wd & 0xFFFFu) != 0u);
        bool cenn = pend && (wd == 0u);
        bool dec = absn || cenn;
        ull mdec = __ballot(dec);
        if (!mdec) {
            __builtin_amdgcn_s_sleep(2);
            if (++sweeps > 2000000L) break;  // safety net: never hang the bench
            continue;
        }
        sweeps = 0;
        ull mcen = __ballot(cenn);
        if (dec) pend = false;

        while (mdec) {
            int ls[4];
            int nb = 0;
            while (nb < 4 && mdec) {
                int l = __ffsll((unsigned long long)mdec) - 1;
                mdec &= mdec - 1;
                ls[nb++] = l;
            }
            #pragma unroll
            for (int j = nb; j < 4; j++) ls[j] = -1;

            int vv[4]; ull kv[4]; unsigned dj[4]; bool cj[4];
            #pragma unroll
            for (int j = 0; j < 4; j++) {
                vv[j] = 0; kv[j] = 0; dj[j] = 0; cj[j] = false;
                if (ls[j] >= 0) {
                    vv[j] = gb + ls[j];
                    cj[j] = (mcen >> ls[j]) & 1ull;
                    dj[j] = cj[j] ? 0xFFFF0001u : 0xFFFF0000u;
                    kv[j] = packkey(hier[vv[j]], vv[j]);
                }
            }
            for (int k0 = 0; k0 < K; k0 += 64) {
                int k = k0 + lane;
                bool kok = k < K;
                #pragma unroll
                for (int j = 0; j < 4; j++) {
                    if (ls[j] >= 0 && kok) {
                        int w = neighs[(size_t)vv[j] * (size_t)K + k];
                        if (w >= 0 && kv[j] > packkey(hier[w], w)) {
                            atomicAdd(&word[w], dj[j]);            // fused pred-release + cen-mark
                            if (cj[j]) atomicMax(&best[w], kv[j]); // absorber record
                        }
                    }
                }
            }
        }
    }
}

// ---------------- fused epilogue: compact -> sync -> rank+rs -> sync -> assign ----------------
#define RTILE 1024
__global__ __launch_bounds__(256, 8)
void k_finish(const float* __restrict__ hier,
              const unsigned* __restrict__ word,
              const ull* __restrict__ best,
              const int* __restrict__ row_splits,
              ull* __restrict__ segKeys,
              int* __restrict__ segIds,
              int* __restrict__ counters,
              int* __restrict__ cidOf,
              int* __restrict__ sel_out,
              int* __restrict__ rs_out,
              int* __restrict__ clus_out,
              int V, int NSEG) {
    cg::grid_group grid = cg::this_grid();
    __shared__ ull tile[RTILE];
    const int t = blockIdx.x * blockDim.x + threadIdx.x;
    const int lane = threadIdx.x & 63;

    // ---- phase 1: compact centers per segment (ballot-batched) ----
    {
        bool isc = (t < V) && ((word[t] & 0xFFFFu) == 0u);
        int s = 0;
        if (isc) { while (s + 1 < NSEG && t >= row_splits[s + 1]) s++; }
        if (__any(isc)) {
            for (int s0 = 0; s0 < NSEG; s0++) {
                ull ms = __ballot(isc && s == s0);
                if (!ms) continue;
                int leader = __ffsll((unsigned long long)ms) - 1;
                int n = __popcll(ms);
                unsigned base = 0;
                if (lane == leader) base = (unsigned)atomicAdd(&counters[s0], n);
                base = (unsigned)__shfl((int)base, leader);
                unsigned pre = (unsigned)__popcll(ms & ((1ull << lane) - 1ull));
                if (isc && s == s0) {
                    int slot = row_splits[s0] + (int)(base + pre);
                    segKeys[slot] = packkey(hier[t], t);
                    segIds[slot] = t;
                }
            }
        }
    }
    grid.sync();

    // ---- phase 2: rank centers -> cid, sel; write rs_out ----
    {
        int s = 0;
        if (t < V) { while (s + 1 < NSEG && t >= row_splits[s + 1]) s++; }
        int rsb = 0;
        for (int i = 0; i < s; i++) rsb += counters[i];
        if (blockIdx.x == 0 && threadIdx.x == 0) {
            int acc = 0;
            rs_out[0] = 0;
            for (int i = 0; i < NSEG; i++) { acc += counters[i]; rs_out[i + 1] = acc; }
        }
        int base = (t < V) ? row_splits[s] : 0;
        int j = (t < V) ? (t - base) : -1;
        int cnt = (t < V) ? counters[s] : 0;
        bool active = (t < V) && (j >= 0) && (j < cnt);
        ull mk = active ? segKeys[t] : 0ull;
        int r = 0;

        int B0 = blockIdx.x * blockDim.x;
        int B1 = min(B0 + (int)blockDim.x - 1, V - 1);
        int sf = 0; while (sf + 1 < NSEG && B0 >= row_splits[sf + 1]) sf++;
        int sl = 0; while (sl + 1 < NSEG && B1 >= row_splits[sl + 1]) sl++;

        for (int s0 = sf; s0 <= sl; s0++) {
            int b0 = row_splits[s0];
            int c0 = counters[s0];
            bool in = active && (s == s0);
            for (int tb = 0; tb < c0; tb += RTILE) {
                int n = min(RTILE, c0 - tb);
                __syncthreads();
                for (int i = threadIdx.x; i < n; i += blockDim.x)
                    tile[i] = segKeys[b0 + tb + i];
                __syncthreads();
                if (in) {
                    int rr = 0;
                    #pragma unroll 8
                    for (int i = 0; i < n; i++) rr += (tile[i] > mk) ? 1 : 0;
                    r += rr;
                }
            }
        }
        if (active) {
            int cid = rsb + r;
            int v = segIds[t];
            cidOf[v] = cid;
            sel_out[cid] = v;
        }
    }
    grid.sync();

    // ---- phase 3: final cluster assignment ----
    if (t < V) {
        ull b = best[t];
        int c;
        if (b == 0ull) {
            c = cidOf[t];                                   // center
        } else {
            uint32_t a = ~(uint32_t)(b & 0xFFFFFFFFull);    // absorber global index
            c = cidOf[a];
        }
        clus_out[t] = c;
    }
}

extern "C" void kernel_launch(void* const* d_in, const int* in_sizes, int n_in,
                              void* d_out, int out_size, void* d_ws, size_t ws_size,
                              hipStream_t stream) {
    const int*   neighs     = (const int*)d_in[0];
    const float* hier       = (const float*)d_in[1];
    const int*   row_splits = (const int*)d_in[2];

    const int V    = in_sizes[1];
    const int K    = in_sizes[0] / V;
    const int NSEG = in_sizes[2] - 1;
    const long E   = (long)V * (long)K;

    int* out      = (int*)d_out;
    int* sel_out  = out;
    int* rs_out   = out + V;
    int* clus_out = out + V + NSEG + 1;

    // ws: [best 8V][word 4V][cnts 128][segKeys 8V][segIds 4V][cidOf 4V]
    char* w = (char*)d_ws;
    ull*      best    = (ull*)(w);
    unsigned* word    = (unsigned*)(w + (size_t)8 * V);
    int*      cnts    = (int*)(w + (size_t)12 * V);
    size_t segOff     = (size_t)12 * V + 128;
    ull*      segKeys = (ull*)(w + segOff);
    int*      segIds  = (int*)(w + segOff + (size_t)8 * V);
    int*      cidOf   = (int*)(w + segOff + (size_t)12 * V);

    const int B  = 256;
    const int gV = (V + B - 1) / B;

    (void)hipMemsetAsync(w, 0, segOff, stream);               // best, word, cnts
    (void)hipMemsetAsync(sel_out, 0xFF, (size_t)4 * V, stream);

    if ((K & 3) == 0) {
        long E4 = E / 4;
        k_build4<<<(int)((E4 + B - 1) / B), B, 0, stream>>>(neighs, hier, word, E4, K);
    } else {
        k_build1<<<(int)((E + B - 1) / B), B, 0, stream>>>(neighs, hier, word, E, K);
    }

    const int G  = (V + 63) >> 6;        // 64-vertex groups
    const int PB = (G + 3) / 4;          // every wave owns exactly one group
    k_propagate<<<PB, B, 0, stream>>>(neighs, hier, word, best, V, K);

    // fused epilogue (cooperative: 1563 blocks <= 2048 co-resident at 8/CU)
    int Vv = V, Ns = NSEG;
    void* args[] = {
        (void*)&hier, (void*)&word, (void*)&best, (void*)&row_splits,
        (void*)&segKeys, (void*)&segIds, (void*)&cnts, (void*)&cidOf,
        (void*)&sel_out, (void*)&rs_out, (void*)&clus_out,
        (void*)&Vv, (void*)&Ns
    };
    (void)hipLaunchCooperativeKernel((void*)k_finish, dim3(gV), dim3(B), args, 0, stream);
}

// Round 19
// 1284.210 us; speedup vs baseline: 1.1718x; 1.1718x over previous
//
#include <hip/hip_runtime.h>
#include <stdint.h>

typedef unsigned long long ull;

static __device__ __forceinline__ ull packkey(float f, int v) {
    uint32_t u = __float_as_uint(f);
    u = (u & 0x80000000u) ? ~u : (u | 0x80000000u);
    return ((ull)u << 32) | (ull)(~(uint32_t)v);
}
static __device__ __forceinline__ unsigned aloadu32(const unsigned* p) {
    return __hip_atomic_load(p, __ATOMIC_RELAXED, __HIP_MEMORY_SCOPE_AGENT);
}

// ---------------- build: in-degree of absorption DAG into pred field (word>>16) ----------------
__global__ void k_build4(const int* __restrict__ neighs, const float* __restrict__ hier,
                         unsigned* __restrict__ word, long E4, int K) {
    long t = (long)blockIdx.x * blockDim.x + threadIdx.x;
    if (t >= E4) return;
    long e = t * 4;
    int u = (int)(e / K);
    ull ku = packkey(hier[u], u);
    int4 w4 = *(const int4*)(neighs + e);
    int ws[4] = {w4.x, w4.y, w4.z, w4.w};
    #pragma unroll
    for (int j = 0; j < 4; j++) {
        int w = ws[j];
        if (w < 0) continue;
        if (ku > packkey(hier[w], w))
            atomicAdd(&word[w], 0x10000u);     // fire-and-forget
    }
}
__global__ void k_build1(const int* __restrict__ neighs, const float* __restrict__ hier,
                         unsigned* __restrict__ word, long E, int K) {
    long e = (long)blockIdx.x * blockDim.x + threadIdx.x;
    if (e >= E) return;
    int w = neighs[e];
    if (w < 0) return;
    int u = (int)(e / K);
    if (packkey(hier[u], u) > packkey(hier[w], w))
        atomicAdd(&word[w], 0x10000u);
}

// ---------------- propagation: owner polls word; fused adds + center maxes ----------------
// word[v] = pred<<16 | cenCount.  ABSORBED: cen>0.  CENTER: word==0.
// Each wave owns exactly ONE 64-vertex group (grid sized so nwaves >= G).
__global__ __launch_bounds__(256, 8)
void k_propagate(const int* __restrict__ neighs, const float* __restrict__ hier,
                 unsigned* __restrict__ word, ull* __restrict__ best,
                 int V, int K) {
    const int gtid = blockIdx.x * blockDim.x + threadIdx.x;
    const int wv = gtid >> 6, lane = gtid & 63;
    const int gb = wv << 6;
    if (gb >= V) return;                     // wave owns nothing; exit immediately
    int v = gb + lane;
    bool pend = v < V;

    long sweeps = 0;
    while (__any(pend)) {
        unsigned wd = 0x7FFF0000u;
        if (pend) wd = aloadu32(&word[v]);
        bool absn = pend && ((wd & 0xFFFFu) != 0u);
        bool cenn = pend && (wd == 0u);
        bool dec = absn || cenn;
        ull mdec = __ballot(dec);
        if (!mdec) {
            __builtin_amdgcn_s_sleep(2);
            if (++sweeps > 2000000L) break;  // safety net: never hang the bench
            continue;
        }
        sweeps = 0;
        ull mcen = __ballot(cenn);
        if (dec) pend = false;

        while (mdec) {
            int ls[4];
            int nb = 0;
            while (nb < 4 && mdec) {
                int l = __ffsll((unsigned long long)mdec) - 1;
                mdec &= mdec - 1;
                ls[nb++] = l;
            }
            #pragma unroll
            for (int j = nb; j < 4; j++) ls[j] = -1;

            int vv[4]; ull kv[4]; unsigned dj[4]; bool cj[4];
            #pragma unroll
            for (int j = 0; j < 4; j++) {
                vv[j] = 0; kv[j] = 0; dj[j] = 0; cj[j] = false;
                if (ls[j] >= 0) {
                    vv[j] = gb + ls[j];
                    cj[j] = (mcen >> ls[j]) & 1ull;
                    dj[j] = cj[j] ? 0xFFFF0001u : 0xFFFF0000u;
                    kv[j] = packkey(hier[vv[j]], vv[j]);
                }
            }
            for (int k0 = 0; k0 < K; k0 += 64) {
                int k = k0 + lane;
                bool kok = k < K;
                #pragma unroll
                for (int j = 0; j < 4; j++) {
                    if (ls[j] >= 0 && kok) {
                        int w = neighs[(size_t)vv[j] * (size_t)K + k];
                        if (w >= 0 && kv[j] > packkey(hier[w], w)) {
                            atomicAdd(&word[w], dj[j]);            // fused pred-release + cen-mark
                            if (cj[j]) atomicMax(&best[w], kv[j]); // absorber record
                        }
                    }
                }
            }
        }
    }
}

// ---------------- compact centers per segment (ballot-batched) ----------------
__global__ void k_compact(const float* __restrict__ hier,
                          const unsigned* __restrict__ word,
                          const int* __restrict__ row_splits,
                          ull* __restrict__ segKeys,
                          int* __restrict__ segIds,
                          int* __restrict__ counters,
                          int V, int NSEG) {
    int v = blockIdx.x * blockDim.x + threadIdx.x;
    int lane = threadIdx.x & 63;
    bool isc = (v < V) && ((word[v] & 0xFFFFu) == 0u);
    int s = 0;
    if (isc) { while (s + 1 < NSEG && v >= row_splits[s + 1]) s++; }
    if (!__any(isc)) return;
    for (int s0 = 0; s0 < NSEG; s0++) {
        ull ms = __ballot(isc && s == s0);
        if (!ms) continue;
        int leader = __ffsll((unsigned long long)ms) - 1;
        int n = __popcll(ms);
        unsigned base = 0;
        if (lane == leader) base = (unsigned)atomicAdd(&counters[s0], n);
        base = (unsigned)__shfl((int)base, leader);
        unsigned pre = (unsigned)__popcll(ms & ((1ull << lane) - 1ull));
        if (isc && s == s0) {
            int slot = row_splits[s0] + (int)(base + pre);
            segKeys[slot] = packkey(hier[v], v);
            segIds[slot] = v;
        }
    }
}

// ---------------- rank centers -> cid, sel (rs prefix computed inline; writes rs_out) ----------------
#define RTILE 1024
__global__ void k_rank(const ull* __restrict__ segKeys,
                       const int* __restrict__ segIds,
                       const int* __restrict__ counters,
                       const int* __restrict__ row_splits,
                       int* __restrict__ cidOf,
                       int* __restrict__ sel_out,
                       int* __restrict__ rs_out,
                       int V, int NSEG) {
    __shared__ ull tile[RTILE];
    // inline prefix of counters (NSEG tiny, uniform)
    int rsb = 0;
    int t = blockIdx.x * blockDim.x + threadIdx.x;   // slot index
    int s = 0;
    if (t < V) { while (s + 1 < NSEG && t >= row_splits[s + 1]) s++; }
    for (int i = 0; i < s; i++) rsb += counters[i];

    if (blockIdx.x == 0 && threadIdx.x == 0) {       // write new row_splits
        int acc = 0;
        rs_out[0] = 0;
        for (int i = 0; i < NSEG; i++) { acc += counters[i]; rs_out[i + 1] = acc; }
    }

    int base = (t < V) ? row_splits[s] : 0;
    int j = (t < V) ? (t - base) : -1;
    int cnt = (t < V) ? counters[s] : 0;
    bool active = (t < V) && (j >= 0) && (j < cnt);
    ull mk = active ? segKeys[t] : 0ull;
    int r = 0;

    // block's slot range spans <=2 segments; uniform per block
    int B0 = blockIdx.x * blockDim.x;
    int B1 = min(B0 + (int)blockDim.x - 1, V - 1);
    int sf = 0; while (sf + 1 < NSEG && B0 >= row_splits[sf + 1]) sf++;
    int sl = 0; while (sl + 1 < NSEG && B1 >= row_splits[sl + 1]) sl++;

    for (int s0 = sf; s0 <= sl; s0++) {
        int b0 = row_splits[s0];
        int c0 = counters[s0];
        bool in = active && (s == s0);
        for (int tb = 0; tb < c0; tb += RTILE) {
            int n = min(RTILE, c0 - tb);
            __syncthreads();
            for (int i = threadIdx.x; i < n; i += blockDim.x)
                tile[i] = segKeys[b0 + tb + i];
            __syncthreads();
            if (in) {
                int rr = 0;
                #pragma unroll 8
                for (int i = 0; i < n; i++) rr += (tile[i] > mk) ? 1 : 0;
                r += rr;
            }
        }
    }
    if (active) {
        int cid = rsb + r;
        int v = segIds[t];
        cidOf[v] = cid;
        sel_out[cid] = v;
    }
}

// ---------------- final cluster assignment ----------------
__global__ void k_assign(const ull* __restrict__ best,
                         const int* __restrict__ cidOf,
                         int* __restrict__ clus_out,
                         int V) {
    int v = blockIdx.x * blockDim.x + threadIdx.x;
    if (v >= V) return;
    ull b = best[v];
    int c;
    if (b == 0ull) {
        c = cidOf[v];                                   // center (never receives a max)
    } else {
        uint32_t a = ~(uint32_t)(b & 0xFFFFFFFFull);    // absorber global index
        c = cidOf[a];
    }
    clus_out[v] = c;
}

extern "C" void kernel_launch(void* const* d_in, const int* in_sizes, int n_in,
                              void* d_out, int out_size, void* d_ws, size_t ws_size,
                              hipStream_t stream) {
    const int*   neighs     = (const int*)d_in[0];
    const float* hier       = (const float*)d_in[1];
    const int*   row_splits = (const int*)d_in[2];

    const int V    = in_sizes[1];
    const int K    = in_sizes[0] / V;
    const int NSEG = in_sizes[2] - 1;
    const long E   = (long)V * (long)K;

    int* out      = (int*)d_out;
    int* sel_out  = out;
    int* rs_out   = out + V;
    int* clus_out = out + V + NSEG + 1;

    // ws: [best 8V][word 4V][cnts 128][segKeys 8V][segIds 4V][cidOf 4V]
    char* w = (char*)d_ws;
    ull*      best    = (ull*)(w);
    unsigned* word    = (unsigned*)(w + (size_t)8 * V);
    int*      cnts    = (int*)(w + (size_t)12 * V);
    size_t segOff     = (size_t)12 * V + 128;
    ull*      segKeys = (ull*)(w + segOff);
    int*      segIds  = (int*)(w + segOff + (size_t)8 * V);
    int*      cidOf   = (int*)(w + segOff + (size_t)12 * V);

    const int B  = 256;
    const int gV = (V + B - 1) / B;

    (void)hipMemsetAsync(w, 0, segOff, stream);               // best, word, cnts
    (void)hipMemsetAsync(sel_out, 0xFF, (size_t)4 * V, stream);

    if ((K & 3) == 0) {
        long E4 = E / 4;
        k_build4<<<(int)((E4 + B - 1) / B), B, 0, stream>>>(neighs, hier, word, E4, K);
    } else {
        k_build1<<<(int)((E + B - 1) / B), B, 0, stream>>>(neighs, hier, word, E, K);
    }

    const int G  = (V + 63) >> 6;        // 64-vertex groups
    const int PB = (G + 3) / 4;          // 4 waves/block -> every wave owns exactly one group
    k_propagate<<<PB, B, 0, stream>>>(neighs, hier, word, best, V, K);

    k_compact<<<gV, B, 0, stream>>>(hier, word, row_splits, segKeys, segIds, cnts, V, NSEG);
    k_rank<<<gV, B, 0, stream>>>(segKeys, segIds, cnts, row_splits,
                                 cidOf, sel_out, rs_out, V, NSEG);
    k_assign<<<gV, B, 0, stream>>>(best, cidOf, clus_out, V);
}